// Round 4
// baseline (96.414 us; speedup 1.0000x reference)
//
#include <hip/hip_runtime.h>
#include <hip/hip_bf16.h>
#include <stdint.h>
#include <math.h>

#define H_HT 26
#define W_HT 122
#define NPIX (H_HT * W_HT)   // 3172
#define NA 60
#define NR 125
#define NROW (NPIX * NA)     // 190320
#define NB 32
#define NC 4
#define NBC (NB * NC)        // 128
#define PH 288
#define PW 800
#define AG 4                 // angles per hough block
#define NG (NA / AG)         // 15 angle-groups

// ---- workspace layout (bytes) ----
#define WS_RI    0                         // uint8 [60*3172]        190320
#define WS_OFF   190336                    // int32 [60*126]          30240
#define WS_LIST  220608                    // uint16[60*3172]        380640
#define WS_PV    601280                    // float [128*15]           7680
#define WS_PI    608960                    // int32 [128*15]           7680

// ---------------- Kernel A: predict-and-verify rho index -------------------
// rho[h,w,a] = xs*cos(theta_a) + ys*sin(theta_a), numpy float64 op order.
// Verify the predicted one-hot slot with a single read; exactly one 1.0 per
// 125-row, so a nonzero hit is proof. Rare mismatch -> scan the row.
__global__ __launch_bounds__(256) void predict_ri(const float* __restrict__ vote,
                                                  uint8_t* __restrict__ ri) {
    __shared__ double s_c[NA], s_s[NA];
    const int tid = threadIdx.x;
    if (tid < NA) {
        double t = (double)(tid * 3) * 0.017453292519943295;  // deg2rad
        s_c[tid] = cos(t);
        s_s[tid] = sin(t);
    }
    __syncthreads();
    int row = blockIdx.x * 256 + tid;            // row = pix*60 + a
    if (row >= NROW) return;
    int pix = row / NA;
    int a   = row - pix * NA;
    int h   = pix / W_HT;
    int w   = pix - h * W_HT;
    double xs = (double)w - 60.5;                // w - 122/2 + 0.5
    double ys = (double)h - 12.5;                // h - 26/2 + 0.5
    // match numpy: mul, mul, add, each rounded (no FMA contraction)
    double rho = __dadd_rn(__dmul_rn(xs, s_c[a]), __dmul_rn(ys, s_s[a]));
    int r = (int)rint(rho) + NR / 2;             // half-even, + 62
    r = r < 0 ? 0 : (r > NR - 1 ? NR - 1 : r);
    const float* vrow = vote + (size_t)row * NR;
    if (vrow[r] == 0.0f) {
        // fallback: find the actual one-hot slot
        for (int r2 = 0; r2 < NR; ++r2) {
            if (vrow[r2] != 0.0f) { r = r2; break; }
        }
    }
    ri[a * NPIX + pix] = (uint8_t)r;
}

// ---------------- Kernel B: invert ri into CSR bucket lists per angle -------
__global__ __launch_bounds__(256) void build_csr(const uint8_t* __restrict__ ri,
                                                 int* __restrict__ off,
                                                 uint16_t* __restrict__ list) {
    __shared__ int s_cnt[NR];
    __shared__ int s_pre[NR + 1];
    __shared__ int s_cur[NR];
    const int a = blockIdx.x;
    const int tid = threadIdx.x;
    for (int i = tid; i < NR; i += 256) s_cnt[i] = 0;
    __syncthreads();
    for (int p = tid; p < NPIX; p += 256)
        atomicAdd(&s_cnt[ri[a * NPIX + p]], 1);
    __syncthreads();
    if (tid == 0) {
        int s = 0;
        for (int r = 0; r < NR; ++r) { s_pre[r] = s; s += s_cnt[r]; }
        s_pre[NR] = s;
    }
    __syncthreads();
    for (int r = tid; r < NR + 1; r += 256) off[a * (NR + 1) + r] = s_pre[r];
    for (int r = tid; r < NR; r += 256) s_cur[r] = s_pre[r];
    __syncthreads();
    for (int p = tid; p < NPIX; p += 256) {
        int r = ri[a * NPIX + p];
        int slot = atomicAdd(&s_cur[r], 1);
        list[a * NPIX + slot] = (uint16_t)p;
    }
}

// ---------------- Kernel C: per-(bc, angle-group) bin sums + partial argmax -
// Phase 1: gather straight from pred in list order (inline nearest-resize
// index math -- identical f32 expressions as validated).
// Phase 2: per-bin contiguous LDS run sum.
__global__ __launch_bounds__(256) void hough_partial(const float* __restrict__ pred,
                                                     const int* __restrict__ off,
                                                     const uint16_t* __restrict__ list,
                                                     float* __restrict__ pv,
                                                     int* __restrict__ pi) {
    __shared__ float s_gath[AG * NPIX];    // 50752 B
    __shared__ float s_rv[256];
    __shared__ int   s_ri2[256];

    const int blk = blockIdx.x;
    const int bc  = blk / NG;
    const int g   = blk - bc * NG;
    const int a0  = g * AG;
    const int tid = threadIdx.x;
    const float C1 = (float)(288.0 / 26.0);
    const float C2 = (float)(800.0 / 122.0);

    const float* pimg = pred + (size_t)bc * PH * PW;
    const uint32_t* lp32 = reinterpret_cast<const uint32_t*>(list + a0 * NPIX);
    for (int j2 = tid; j2 < AG * NPIX / 2; j2 += 256) {
        uint32_t w2 = lp32[j2];
        int p0 = w2 & 0xffffu;
        int p1 = w2 >> 16;
        int h0 = p0 / W_HT, w0 = p0 - h0 * W_HT;
        int h1 = p1 / W_HT, w1 = p1 - h1 * W_HT;
        int hi0 = (int)floorf((float)h0 * C1), wi0 = (int)floorf((float)w0 * C2);
        int hi1 = (int)floorf((float)h1 * C1), wi1 = (int)floorf((float)w1 * C2);
        s_gath[j2 * 2]     = pimg[hi0 * PW + wi0];
        s_gath[j2 * 2 + 1] = pimg[hi1 * PW + wi1];
    }
    __syncthreads();

    float bv = -1.0f; int bi = 0;
    for (int lb = tid; lb < AG * NR; lb += 256) {
        int la = lb / NR;
        int r  = lb - la * NR;
        int a  = a0 + la;
        int o0 = off[a * (NR + 1) + r];
        int o1 = off[a * (NR + 1) + r + 1];
        const float* gp = s_gath + la * NPIX;
        float s0 = 0.0f, s1 = 0.0f;
        int j = o0;
        for (; j + 1 < o1; j += 2) { s0 += gp[j]; s1 += gp[j + 1]; }
        if (j < o1) s0 += gp[j];
        float s = s0 + s1;
        int gbin = a * NR + r;
        if (s > bv) { bv = s; bi = gbin; }
    }
    s_rv[tid] = bv; s_ri2[tid] = bi;
    __syncthreads();
    for (int s = 128; s > 0; s >>= 1) {
        if (tid < s) {
            float ov = s_rv[tid + s]; int oi = s_ri2[tid + s];
            if (ov > s_rv[tid] || (ov == s_rv[tid] && oi < s_ri2[tid])) {
                s_rv[tid] = ov; s_ri2[tid] = oi;
            }
        }
        __syncthreads();
    }
    if (tid == 0) { pv[blk] = s_rv[0]; pi[blk] = s_ri2[0]; }
}

// ---------------- Kernel D: final argmax + gather + L1-normalize + loss -----
__global__ __launch_bounds__(64) void loss_kernel(const float* __restrict__ ht,
                                                  const float* __restrict__ pexist,
                                                  const float* __restrict__ pv,
                                                  const int* __restrict__ pi,
                                                  float* __restrict__ out) {
    const int b = blockIdx.x;
    const int l = threadIdx.x;
    const int p = l >> 2;     // pair 0..15
    const int s = l & 3;      // sub-lane within pair
    const int c = p >> 2;     // channel for ht
    const int k = p & 3;      // channel for idx/exist

    const int bck = b * 4 + k;
    float bv = -1.0f; int fidx = 0x7fffffff;
    for (int g2 = 0; g2 < NG; ++g2) {
        float v = pv[bck * NG + g2];
        int   i = pi[bck * NG + g2];
        if (v > bv || (v == bv && i < fidx)) { bv = v; fidx = i; }
    }

    int a0 = fidx / NR;
    int r  = fidx - a0 * NR;
    const float* htc = ht + (size_t)((b * 4 + c) * NA) * NR;

    float acc = 0.0f;
    for (int a = s; a < NA; a += 4) acc += fabsf(htc[a * NR + r]);
    acc += __shfl_xor(acc, 1);
    acc += __shfl_xor(acc, 2);

    float term = 0.0f;
    if (s == 0) {
        float l1 = fmaxf(acc, 1e-12f);
        float gg = htc[a0 * NR + r] / l1;
        float ex = (pexist[b * 4 + k] > 0.9f) ? 1.0f : 0.0f;
        term = -logf(gg + 1e-12f) * ex;
    }
    for (int offt = 32; offt > 0; offt >>= 1) term += __shfl_down(term, offt);
    if (l == 0) out[b] = term * (1.0f / 16.0f);
}

extern "C" void kernel_launch(void* const* d_in, const int* in_sizes, int n_in,
                              void* d_out, int out_size, void* d_ws, size_t ws_size,
                              hipStream_t stream) {
    const float* ht     = (const float*)d_in[0];
    const float* pred   = (const float*)d_in[1];
    const float* pexist = (const float*)d_in[2];
    const float* vote   = (const float*)d_in[3];

    char* ws = (char*)d_ws;
    uint8_t*  ri   = (uint8_t*) (ws + WS_RI);
    int*      off  = (int*)     (ws + WS_OFF);
    uint16_t* list = (uint16_t*)(ws + WS_LIST);
    float*    pv   = (float*)   (ws + WS_PV);
    int*      pi   = (int*)     (ws + WS_PI);

    predict_ri<<<(NROW + 255) / 256, 256, 0, stream>>>(vote, ri);
    build_csr<<<NA, 256, 0, stream>>>(ri, off, list);
    hough_partial<<<NBC * NG, 256, 0, stream>>>(pred, off, list, pv, pi);
    loss_kernel<<<NB, 64, 0, stream>>>(ht, pexist, pv, pi, (float*)d_out);
}

// Round 5
// 86.858 us; speedup vs baseline: 1.1100x; 1.1100x over previous
//
#include <hip/hip_runtime.h>
#include <hip/hip_bf16.h>
#include <stdint.h>
#include <math.h>

#define H_HT 26
#define W_HT 122
#define NPIX (H_HT * W_HT)   // 3172
#define NA 60
#define NR 125
#define NROW (NPIX * NA)     // 190320
#define NB 32
#define NC 4
#define NBC (NB * NC)        // 128
#define PH 288
#define PW 800
#define AG2 15               // angles per hough block
#define NG2 4                // angle-groups

#define PRED_BLKS ((NROW + 255) / 256)   // 744
#define GATH_BLKS (NBC * 4)              // 512, 793 pixels each

// ---- workspace layout (bytes) ----
#define WS_RI    0                         // uint8 [60*3172]        190320
#define WS_OFF   190336                    // int32 [60*126]          30240
#define WS_LIST  220608                    // uint16[60*3172]        380640
#define WS_PREDS 601280                    // float [128*3172]      1624064
#define WS_PV    2225344                   // float [128*4]            2048
#define WS_PI    2227392                   // int32 [128*4]            2048

// ---------------- Kernel A: predict-and-verify rho index + gather pred_s ----
// Blocks [0, PRED_BLKS): rho[h,w,a] = xs*cos + ys*sin in numpy f64 op order;
// verify predicted one-hot slot with one read (exactly one 1.0 per row),
// fallback row scan on mismatch. Blocks [PRED_BLKS, +GATH_BLKS): materialize
// nearest-resized pred_s (independent work, fused to save a launch).
__global__ __launch_bounds__(256) void prep(const float* __restrict__ vote,
                                            const float* __restrict__ pred,
                                            uint8_t* __restrict__ ri,
                                            float* __restrict__ pred_s) {
    const int tid = threadIdx.x;
    if (blockIdx.x < PRED_BLKS) {
        __shared__ double s_c[NA], s_s[NA];
        if (tid < NA) {
            double t = (double)(tid * 3) * 0.017453292519943295;  // deg2rad
            s_c[tid] = cos(t);
            s_s[tid] = sin(t);
        }
        __syncthreads();
        int row = blockIdx.x * 256 + tid;            // row = pix*60 + a
        if (row >= NROW) return;
        int pix = row / NA;
        int a   = row - pix * NA;
        int h   = pix / W_HT;
        int w   = pix - h * W_HT;
        double xs = (double)w - 60.5;                // w - 122/2 + 0.5
        double ys = (double)h - 12.5;                // h - 26/2 + 0.5
        double rho = __dadd_rn(__dmul_rn(xs, s_c[a]), __dmul_rn(ys, s_s[a]));
        int r = (int)rint(rho) + NR / 2;             // half-even, + 62
        r = r < 0 ? 0 : (r > NR - 1 ? NR - 1 : r);
        const float* vrow = vote + (size_t)row * NR;
        if (vrow[r] == 0.0f) {
            for (int r2 = 0; r2 < NR; ++r2) {
                if (vrow[r2] != 0.0f) { r = r2; break; }
            }
        }
        ri[a * NPIX + pix] = (uint8_t)r;
    } else {
        const int bidx = blockIdx.x - PRED_BLKS;
        const int bc = bidx >> 2;
        const int q  = bidx & 3;
        const float C1 = (float)(288.0 / 26.0);
        const float C2 = (float)(800.0 / 122.0);
        const float* pimg = pred + (size_t)bc * PH * PW;
        for (int p = q * 793 + tid; p < (q + 1) * 793; p += 256) {
            int h = p / W_HT;
            int w = p - h * W_HT;
            int hi = (int)floorf((float)h * C1);
            int wi = (int)floorf((float)w * C2);
            pred_s[bc * NPIX + p] = pimg[hi * PW + wi];
        }
    }
}

// ---------------- Kernel B: invert ri into CSR bucket lists per angle -------
__global__ __launch_bounds__(256) void build_csr(const uint8_t* __restrict__ ri,
                                                 int* __restrict__ off,
                                                 uint16_t* __restrict__ list) {
    __shared__ int s_cnt[NR];
    __shared__ int s_pre[NR + 1];
    __shared__ int s_cur[NR];
    const int a = blockIdx.x;
    const int tid = threadIdx.x;
    for (int i = tid; i < NR; i += 256) s_cnt[i] = 0;
    __syncthreads();
    for (int p = tid; p < NPIX; p += 256)
        atomicAdd(&s_cnt[ri[a * NPIX + p]], 1);
    __syncthreads();
    if (tid == 0) {
        int s = 0;
        for (int r = 0; r < NR; ++r) { s_pre[r] = s; s += s_cnt[r]; }
        s_pre[NR] = s;
    }
    __syncthreads();
    for (int r = tid; r < NR + 1; r += 256) off[a * (NR + 1) + r] = s_pre[r];
    for (int r = tid; r < NR; r += 256) s_cur[r] = s_pre[r];
    __syncthreads();
    for (int p = tid; p < NPIX; p += 256) {
        int r = ri[a * NPIX + p];
        int slot = atomicAdd(&s_cur[r], 1);
        list[a * NPIX + slot] = (uint16_t)p;
    }
}

// ---------------- Kernel C: per-(bc, 15-angle group) bin sums + argmax ------
// s_pred staged coalesced from pred_s (L2-resident); list read sequentially
// from global (L2 broadcast across blocks); bins summed from LDS.
__global__ __launch_bounds__(256) void hough15(const float* __restrict__ pred_s,
                                               const int* __restrict__ off,
                                               const uint16_t* __restrict__ list,
                                               float* __restrict__ pv,
                                               int* __restrict__ pi) {
    __shared__ float s_pred[NPIX];
    __shared__ float s_rv[256];
    __shared__ int   s_ri2[256];

    const int blk = blockIdx.x;
    const int bc  = blk >> 2;
    const int g   = blk & 3;
    const int a0  = g * AG2;
    const int tid = threadIdx.x;

    {   // coalesced float4 stage: 3172 floats = 793 float4
        const float4* src = reinterpret_cast<const float4*>(pred_s + bc * NPIX);
        float4* dst = reinterpret_cast<float4*>(s_pred);
        for (int i = tid; i < NPIX / 4; i += 256) dst[i] = src[i];
    }
    __syncthreads();

    float bv = -1.0f; int bi = 0;
    for (int lb = tid; lb < AG2 * NR; lb += 256) {
        int la = lb / NR;
        int r  = lb - la * NR;
        int a  = a0 + la;
        int rowb = a * (NR + 1) + r;
        int o0 = off[rowb];
        int o1 = off[rowb + 1];
        const uint16_t* lp = list + a * NPIX;
        float s0 = 0.0f, s1 = 0.0f;
        int j = o0;
        for (; j + 1 < o1; j += 2) { s0 += s_pred[lp[j]]; s1 += s_pred[lp[j + 1]]; }
        if (j < o1) s0 += s_pred[lp[j]];
        float s = s0 + s1;
        int gbin = a * NR + r;
        if (s > bv) { bv = s; bi = gbin; }
    }
    s_rv[tid] = bv; s_ri2[tid] = bi;
    __syncthreads();
    for (int s = 128; s > 0; s >>= 1) {
        if (tid < s) {
            float ov = s_rv[tid + s]; int oi = s_ri2[tid + s];
            if (ov > s_rv[tid] || (ov == s_rv[tid] && oi < s_ri2[tid])) {
                s_rv[tid] = ov; s_ri2[tid] = oi;
            }
        }
        __syncthreads();
    }
    if (tid == 0) { pv[blk] = s_rv[0]; pi[blk] = s_ri2[0]; }
}

// ---------------- Kernel D: final argmax + gather + L1-normalize + loss -----
__global__ __launch_bounds__(64) void loss_kernel(const float* __restrict__ ht,
                                                  const float* __restrict__ pexist,
                                                  const float* __restrict__ pv,
                                                  const int* __restrict__ pi,
                                                  float* __restrict__ out) {
    const int b = blockIdx.x;
    const int l = threadIdx.x;
    const int p = l >> 2;     // pair 0..15
    const int s = l & 3;      // sub-lane within pair
    const int c = p >> 2;     // channel for ht
    const int k = p & 3;      // channel for idx/exist

    const int bck = b * 4 + k;
    float bv = -1.0f; int fidx = 0x7fffffff;
    for (int g2 = 0; g2 < NG2; ++g2) {
        float v = pv[bck * NG2 + g2];
        int   i = pi[bck * NG2 + g2];
        if (v > bv || (v == bv && i < fidx)) { bv = v; fidx = i; }
    }

    int a0 = fidx / NR;
    int r  = fidx - a0 * NR;
    const float* htc = ht + (size_t)((b * 4 + c) * NA) * NR;

    float acc = 0.0f;
    for (int a = s; a < NA; a += 4) acc += fabsf(htc[a * NR + r]);
    acc += __shfl_xor(acc, 1);
    acc += __shfl_xor(acc, 2);

    float term = 0.0f;
    if (s == 0) {
        float l1 = fmaxf(acc, 1e-12f);
        float gg = htc[a0 * NR + r] / l1;
        float ex = (pexist[b * 4 + k] > 0.9f) ? 1.0f : 0.0f;
        term = -logf(gg + 1e-12f) * ex;
    }
    for (int offt = 32; offt > 0; offt >>= 1) term += __shfl_down(term, offt);
    if (l == 0) out[b] = term * (1.0f / 16.0f);
}

extern "C" void kernel_launch(void* const* d_in, const int* in_sizes, int n_in,
                              void* d_out, int out_size, void* d_ws, size_t ws_size,
                              hipStream_t stream) {
    const float* ht     = (const float*)d_in[0];
    const float* pred   = (const float*)d_in[1];
    const float* pexist = (const float*)d_in[2];
    const float* vote   = (const float*)d_in[3];

    char* ws = (char*)d_ws;
    uint8_t*  ri     = (uint8_t*) (ws + WS_RI);
    int*      off    = (int*)     (ws + WS_OFF);
    uint16_t* list   = (uint16_t*)(ws + WS_LIST);
    float*    pred_s = (float*)   (ws + WS_PREDS);
    float*    pv     = (float*)   (ws + WS_PV);
    int*      pi     = (int*)     (ws + WS_PI);

    prep<<<PRED_BLKS + GATH_BLKS, 256, 0, stream>>>(vote, pred, ri, pred_s);
    build_csr<<<NA, 256, 0, stream>>>(ri, off, list);
    hough15<<<NBC * NG2, 256, 0, stream>>>(pred_s, off, list, pv, pi);
    loss_kernel<<<NB, 64, 0, stream>>>(ht, pexist, pv, pi, (float*)d_out);
}